// Round 11
// baseline (63.145 us; speedup 1.0000x reference)
//
#include <hip/hip_runtime.h>
#include <hip/hip_bf16.h>

typedef __attribute__((ext_vector_type(8))) short bf16x8;
typedef __attribute__((ext_vector_type(4))) short bf16x4;
typedef __attribute__((ext_vector_type(4))) float f32x4;
typedef __attribute__((ext_vector_type(4))) unsigned int u32x4;
typedef __attribute__((ext_vector_type(2))) unsigned int u32x2;

#define NC   16
#define IMG  (256*256)

// LDS layout — VERBATIM R3/R8/R10 (passed):
//   p   [256 rows][112 B] @ 0
//   w1t [128 rows][112 B] @ 28672
//   w2t [16 rows][272 B]  @ 43008
//   b1  f32[128] @ 47360 ; b2 f32[16] @ 47872
// Per-wave bounce slice 10752 B (4 x 10752 = 43008 <= W2_OFF: w2t/b1/b2 never
// touched). h is DOUBLE-BUFFERED: h[par] @ wv*10752 + par*4352 (par = pt&1).
// p/w1t are dead there after the register preloads + barrier 2 (R10-proven).
#define P_STRIDE  112
#define W1_OFF    28672
#define W1_STRIDE 112
#define W2_OFF    43008
#define B1_OFF    47360
#define B2_OFF    47872
#define LDS_TOT   47936
#define BNC_SZ    10752
#define H_BUF     4352

static __device__ __forceinline__ unsigned short f2bf(float f) {
    union { __hip_bfloat16 h; unsigned short u; } cv;
    cv.h = __float2bfloat16(f);
    return cv.u;
}
static __device__ __forceinline__ unsigned int packbf2(float a, float b) {
    return (unsigned int)f2bf(a) | ((unsigned int)f2bf(b) << 16);
}
static __device__ __forceinline__ f32x4 mfma_bf16_16x16x16(bf16x4 a, bf16x4 b, f32x4 c) {
#if __has_builtin(__builtin_amdgcn_mfma_f32_16x16x16bf16_1k)
    return __builtin_amdgcn_mfma_f32_16x16x16bf16_1k(a, b, c, 0, 0, 0);
#else
    f32x4 d;
    asm("v_mfma_f32_16x16x16_bf16 %0, %1, %2, %3" : "=v"(d) : "v"(a), "v"(b), "v"(c));
    return d;
#endif
}

// ---------------------------------------------------------------------------
// Pass 1: R10-verified skeleton. Single delta: h double-buffer (par = pt&1)
// -> ONE lgkmcnt wall per pt (between h-write and h-read). The pre-write WAR
// wall is redundant: conflicting reads (pt-2) completed at pt-1's wall.
// ---------------------------------------------------------------------------
__global__ __launch_bounds__(256, 3) void nca_update_mfma(
    const float* __restrict__ x, const float* __restrict__ rand_vals,
    const float* __restrict__ w1, const float* __restrict__ b1,
    const float* __restrict__ w2, const float* __restrict__ b2,
    float* __restrict__ out, float* __restrict__ alpha_ws)
{
    __shared__ __align__(16) unsigned char lds[LDS_TOT];
    const int t = threadIdx.x;
    const int wv = t >> 6, l15 = t & 15, lg = (t >> 4) & 3;

    // XCD-bijective swizzle (4096 = 8 x 512): halo rows share an XCD L2.
    const int wg = (blockIdx.x & 7) * 512 + (blockIdx.x >> 3);
    const int b  = wg >> 8;
    const int h  = wg & 255;
    const int w  = t;

    // ---- stage weights (R3/R8/R10-verbatim mappings) ----
    #pragma unroll
    for (int i = 0; i < 24; i++) {               // w1 (48x128) -> w1t[n][k]
        int idx = i*256 + t;
        int n = idx & 127, k = idx >> 7;
        *(unsigned short*)(lds + W1_OFF + n*W1_STRIDE + k*2) = f2bf(w1[k*128 + n]);
    }
    #pragma unroll
    for (int i = 0; i < 8; i++) {                // w2 (128x16) -> w2t[c][k]
        int idx = i*256 + t;
        int c = idx & 15, k = idx >> 4;
        *(unsigned short*)(lds + W2_OFF + c*272 + k*2) = f2bf(w2[k*16 + c]);
    }
    if (t < 128) *(float*)(lds + B1_OFF + t*4) = b1[t];
    if (t < 16)  *(float*)(lds + B2_OFF + t*4) = b2[t];

    // ---- perceive (fp32, wrap), double-buffered channel pairs ----
    const int hm = (h + 255) & 255, hp = (h + 1) & 255;
    const int wm = (w + 255) & 255, wp = (w + 1) & 255;
    const float* xb = x + (size_t)b * NC * IMG;
    const int r0o = hm*256, r1o = h*256, r2o = hp*256;

    const float rv = rand_vals[b*IMG + r1o + w];   // early issue

    float buf[2][18];
    unsigned int pk[24];
    float premax = 0.0f;

    #pragma unroll
    for (int cc = 0; cc < 2; cc++) {             // channels 0,1
        const float* xc_ = xb + cc*IMG;
        float* bu = &buf[0][cc*9];
        bu[0]=xc_[r0o+wm]; bu[1]=xc_[r0o+w]; bu[2]=xc_[r0o+wp];
        bu[3]=xc_[r1o+wm]; bu[4]=xc_[r1o+w]; bu[5]=xc_[r1o+wp];
        bu[6]=xc_[r2o+wm]; bu[7]=xc_[r2o+w]; bu[8]=xc_[r2o+wp];
    }
    #pragma unroll
    for (int pr = 0; pr < 8; pr++) {
        if (pr < 7) {                            // prefetch next pair
            #pragma unroll
            for (int cc = 0; cc < 2; cc++) {
                const float* xc_ = xb + ((pr+1)*2 + cc)*IMG;
                float* bu = &buf[(pr+1)&1][cc*9];
                bu[0]=xc_[r0o+wm]; bu[1]=xc_[r0o+w]; bu[2]=xc_[r0o+wp];
                bu[3]=xc_[r1o+wm]; bu[4]=xc_[r1o+w]; bu[5]=xc_[r1o+wp];
                bu[6]=xc_[r2o+wm]; bu[7]=xc_[r2o+w]; bu[8]=xc_[r2o+wp];
            }
        }
        float pv[6];
        #pragma unroll
        for (int cc = 0; cc < 2; cc++) {         // channels 2pr, 2pr+1
            const float* a = &buf[pr&1][cc*9];
            pv[cc*3+0] = a[4];
            pv[cc*3+1] = 0.125f*(a[2]-a[0]) + 0.25f*(a[5]-a[3]) + 0.125f*(a[8]-a[6]);
            pv[cc*3+2] = 0.125f*(a[6]-a[0]) + 0.25f*(a[7]-a[1]) + 0.125f*(a[8]-a[2]);
            if (pr*2 + cc == 3)                  // fused pre_life pool (alpha)
                premax = fmaxf(fmaxf(fmaxf(a[0],a[1]),fmaxf(a[2],a[3])),
                         fmaxf(fmaxf(a[4],a[5]),fmaxf(fmaxf(a[6],a[7]),a[8])));
        }
        pk[pr*3+0] = packbf2(pv[0], pv[1]);
        pk[pr*3+1] = packbf2(pv[2], pv[3]);
        pk[pr*3+2] = packbf2(pv[4], pv[5]);
    }

    {   // stage p row (48 bf16, 112 B stride) — verbatim
        u32x4* pvv = (u32x4*)(lds + t*P_STRIDE);
        #pragma unroll
        for (int j = 0; j < 6; j++) {
            u32x4 v = {pk[4*j], pk[4*j+1], pk[4*j+2], pk[4*j+3]};
            pvv[j] = v;
        }
    }

    // per-pixel fire/life bits (own registers; shfl'd to storing lanes later)
    const int bits = ((rv < 0.5f) ? 1 : 0) | ((premax > 0.1f) ? 2 : 0);

    // x-centers in GEMM2-fragment layout, preloaded pre-barrier (L1/L2-hot).
    float xcf[4][4];
    #pragma unroll
    for (int pt = 0; pt < 4; pt++) {
        const float* xp = xb + r1o + (wv*64 + pt*16 + l15);
        #pragma unroll
        for (int r = 0; r < 4; r++)
            xcf[pt][r] = xp[(size_t)(lg*4 + r) * IMG];
    }

    __syncthreads();   // barrier 1: staging complete

    // ---- preload ALL fragments to registers (verbatim) ----
    bf16x8 A1a[8]; bf16x4 A1b[8];                // w1t rows (hidden-major)
    #pragma unroll
    for (int mt = 0; mt < 8; mt++) {
        const unsigned char* r = lds + W1_OFF + (mt*16 + l15)*W1_STRIDE;
        A1a[mt] = *(const bf16x8*)(r + lg*16);
        A1b[mt] = *(const bf16x4*)(r + 64 + lg*8);
    }
    bf16x8 Bpa[4]; bf16x4 Bpb[4];                // p cols (pixel-major)
    #pragma unroll
    for (int pt = 0; pt < 4; pt++) {
        const unsigned char* r = lds + (wv*64 + pt*16 + l15)*P_STRIDE;
        Bpa[pt] = *(const bf16x8*)(r + lg*16);
        Bpb[pt] = *(const bf16x4*)(r + 64 + lg*8);
    }
    bf16x8 A2[4];                                // w2t rows (channel-major)
    #pragma unroll
    for (int kt = 0; kt < 4; kt++)
        A2[kt] = *(const bf16x8*)(lds + W2_OFF + l15*272 + kt*64 + lg*16);
    f32x4 b2frag = *(const f32x4*)(lds + B2_OFF + lg*16);

    asm volatile("s_waitcnt lgkmcnt(0)" ::: "memory");
    __builtin_amdgcn_sched_barrier(0);
    __syncthreads();   // barrier 2: all preloads done; bounce regions free

    unsigned char* hb0 = lds + wv*BNC_SZ;        // h double-buffer base
    const size_t obase = (size_t)b*NC*IMG + r1o;

    #pragma unroll
    for (int pt = 0; pt < 4; pt++) {
        unsigned char* hb = hb0 + (pt & 1)*H_BUF;   // h[par] [16 pix][272 B]
        // GEMM1: h[hidden][pixel-tile], bias from LDS into accumulator
        f32x4 hacc[8];
        __builtin_amdgcn_s_setprio(1);
        #pragma unroll
        for (int mt = 0; mt < 8; mt++) {
            f32x4 a = *(const f32x4*)(lds + B1_OFF + (mt*16 + lg*4)*4);
            a = __builtin_amdgcn_mfma_f32_16x16x32_bf16(A1a[mt], Bpa[pt], a, 0,0,0);
            a = mfma_bf16_16x16x16(A1b[mt], Bpb[pt], a);
            hacc[mt] = a;
        }
        __builtin_amdgcn_s_setprio(0);
        // h write to buffer (pt&1). No pre-write wall: reads of this buffer
        // (iteration pt-2) completed at pt-1's wall; program order pinned by
        // the sched_barriers at each wall.
        #pragma unroll
        for (int mt = 0; mt < 8; mt++) {
            u32x2 pk2 = {packbf2(fmaxf(hacc[mt][0],0.f), fmaxf(hacc[mt][1],0.f)),
                         packbf2(fmaxf(hacc[mt][2],0.f), fmaxf(hacc[mt][3],0.f))};
            *(u32x2*)(hb + l15*272 + mt*32 + lg*8) = pk2;
        }
        asm volatile("s_waitcnt lgkmcnt(0)" ::: "memory");   // RAW: h ready
        __builtin_amdgcn_sched_barrier(0);
        // GEMM2: dx[chan][pixel-tile]
        f32x4 acc2 = b2frag;
        __builtin_amdgcn_s_setprio(1);
        #pragma unroll
        for (int kt = 0; kt < 4; kt++) {
            bf16x8 Bh = *(const bf16x8*)(hb + l15*272 + kt*64 + lg*16);
            acc2 = __builtin_amdgcn_mfma_f32_16x16x32_bf16(A2[kt], Bh, acc2, 0,0,0);
        }
        __builtin_amdgcn_s_setprio(0);
        // ---- direct-store epilogue from D2 fragment layout (R10-verbatim) ----
        const int bt = __shfl(bits, pt*16 + l15, 64);
        const float fm = (bt & 1) ? 1.0f : 0.0f;
        const float lf = (bt & 2) ? 1.0f : 0.0f;
        const int pix = wv*64 + pt*16 + l15;
        float* op = out + obase + pix;
        #pragma unroll
        for (int r = 0; r < 4; r++)
            op[(size_t)(lg*4 + r) * IMG] = fmaf(acc2[r], fm, xcf[pt][r]) * lf;
        if (lg == 0)   // c==3 lives in lg==0, r==3; alpha_new is unmasked
            alpha_ws[b*IMG + r1o + pix] = fmaf(acc2[3], fm, xcf[pt][3]);
    }
}

// ---------------------------------------------------------------------------
// Pass 2: post_life pool over alpha_new; zero the (rare) dead pixels.
// ---------------------------------------------------------------------------
__global__ __launch_bounds__(256) void nca_postmask(
    const float* __restrict__ alpha_ws, float* __restrict__ out)
{
    const int wg = (blockIdx.x & 7) * 512 + (blockIdx.x >> 3);
    const int b  = wg >> 8;
    const int h  = wg & 255;
    const int w  = threadIdx.x;
    const int hm = (h + 255) & 255, hp = (h + 1) & 255;
    const int wm = (w + 255) & 255, wp = (w + 1) & 255;

    const float* na = alpha_ws + b*IMG;
    const float* n0 = na + hm*256;
    const float* n1 = na + h *256;
    const float* n2 = na + hp*256;
    float post = fmaxf(fmaxf(fmaxf(n0[wm],n0[w]),fmaxf(n0[wp],n1[wm])),
                 fmaxf(fmaxf(n1[w],n1[wp]),fmaxf(fmaxf(n2[wm],n2[w]),n2[wp])));
    if (!(post > 0.1f)) {
        float* ob = out + (size_t)b*NC*IMG + h*256 + w;
        #pragma unroll
        for (int c = 0; c < 16; c++) ob[c*IMG] = 0.0f;
    }
}

extern "C" void kernel_launch(void* const* d_in, const int* in_sizes, int n_in,
                              void* d_out, int out_size, void* d_ws, size_t ws_size,
                              hipStream_t stream) {
    const float* x         = (const float*)d_in[0];
    const float* rand_vals = (const float*)d_in[1];
    const float* w1        = (const float*)d_in[2];
    const float* b1        = (const float*)d_in[3];
    const float* w2        = (const float*)d_in[4];
    const float* b2        = (const float*)d_in[5];
    float* out      = (float*)d_out;
    float* alpha_ws = (float*)d_ws;   // 4 MB

    const int grid = 16 * 256;
    nca_update_mfma<<<grid, 256, 0, stream>>>(x, rand_vals, w1, b1, w2, b2,
                                              out, alpha_ws);
    nca_postmask<<<grid, 256, 0, stream>>>(alpha_ws, out);
}

// Round 14
// 61.832 us; speedup vs baseline: 1.0212x; 1.0212x over previous
//
#include <hip/hip_runtime.h>
#include <hip/hip_bf16.h>

typedef __attribute__((ext_vector_type(8))) short bf16x8;
typedef __attribute__((ext_vector_type(4))) short bf16x4;
typedef __attribute__((ext_vector_type(4))) float f32x4;
typedef __attribute__((ext_vector_type(4))) unsigned int u32x4;
typedef __attribute__((ext_vector_type(2))) unsigned int u32x2;

#define NC   16
#define IMG  (256*256)

// LDS layout — VERBATIM from the round-3 kernel that passed at 62.7 us.
//   p   [256 rows][112 B] @ 0
//   w1t [128 rows][112 B] @ 28672
//   w2t [16 rows][272 B]  @ 43008
//   b1  f32[128] @ 47360 ; b2 f32[16] @ 47872
// Per-wave bounce (aliases p/w1t AFTER all fragments preloaded to registers
// and barrier 2): h [16][272 B] @ wv*9472 ; dx f32 [64][80 B] @ wv*9472+4352.
#define P_STRIDE  112
#define W1_OFF    28672
#define W1_STRIDE 112
#define W2_OFF    43008
#define B1_OFF    47360
#define B2_OFF    47872
#define LDS_TOT   47936
#define BNC_SZ    9472
#define BNC_DX    4352

static __device__ __forceinline__ unsigned short f2bf(float f) {
    union { __hip_bfloat16 h; unsigned short u; } cv;
    cv.h = __float2bfloat16(f);
    return cv.u;
}
static __device__ __forceinline__ unsigned int packbf2(float a, float b) {
    return (unsigned int)f2bf(a) | ((unsigned int)f2bf(b) << 16);
}
static __device__ __forceinline__ f32x4 mfma_bf16_16x16x16(bf16x4 a, bf16x4 b, f32x4 c) {
#if __has_builtin(__builtin_amdgcn_mfma_f32_16x16x16bf16_1k)
    return __builtin_amdgcn_mfma_f32_16x16x16bf16_1k(a, b, c, 0, 0, 0);
#else
    f32x4 d;
    asm("v_mfma_f32_16x16x16_bf16 %0, %1, %2, %3" : "=v"(d) : "v"(a), "v"(b), "v"(c));
    return d;
#endif
}

// ---------------------------------------------------------------------------
// Pass 1: R3-verified skeleton. Register-only deltas: double-buffered perceive
// loads, centers kept in registers, early rand load, setprio around MFMA.
// ---------------------------------------------------------------------------
__global__ __launch_bounds__(256, 3) void nca_update_mfma(
    const float* __restrict__ x, const float* __restrict__ rand_vals,
    const float* __restrict__ w1, const float* __restrict__ b1,
    const float* __restrict__ w2, const float* __restrict__ b2,
    float* __restrict__ out, float* __restrict__ alpha_ws)
{
    __shared__ __align__(16) unsigned char lds[LDS_TOT];
    const int t = threadIdx.x;

    // XCD-bijective swizzle (4096 = 8 x 512): halo rows share an XCD L2.
    const int wg = (blockIdx.x & 7) * 512 + (blockIdx.x >> 3);
    const int b  = wg >> 8;
    const int h  = wg & 255;
    const int w  = t;

    // ---- stage weights (R3-verbatim mappings) ----
    #pragma unroll
    for (int i = 0; i < 24; i++) {               // w1 (48x128) -> w1t[n][k]
        int idx = i*256 + t;
        int n = idx & 127, k = idx >> 7;
        *(unsigned short*)(lds + W1_OFF + n*W1_STRIDE + k*2) = f2bf(w1[k*128 + n]);
    }
    #pragma unroll
    for (int i = 0; i < 8; i++) {                // w2 (128x16) -> w2t[c][k]
        int idx = i*256 + t;
        int c = idx & 15, k = idx >> 4;
        *(unsigned short*)(lds + W2_OFF + c*272 + k*2) = f2bf(w2[k*16 + c]);
    }
    if (t < 128) *(float*)(lds + B1_OFF + t*4) = b1[t];
    if (t < 16)  *(float*)(lds + B2_OFF + t*4) = b2[t];

    // ---- perceive (fp32, wrap), double-buffered channel pairs ----
    const int hm = (h + 255) & 255, hp = (h + 1) & 255;
    const int wm = (w + 255) & 255, wp = (w + 1) & 255;
    const float* xb = x + (size_t)b * NC * IMG;
    const int r0o = hm*256, r1o = h*256, r2o = hp*256;

    const float rv = rand_vals[b*IMG + r1o + w];   // early issue

    float buf[2][18];
    unsigned int pk[24];
    float xc[16];
    float premax = 0.0f;

    #pragma unroll
    for (int cc = 0; cc < 2; cc++) {             // channels 0,1
        const float* xc_ = xb + cc*IMG;
        float* bu = &buf[0][cc*9];
        bu[0]=xc_[r0o+wm]; bu[1]=xc_[r0o+w]; bu[2]=xc_[r0o+wp];
        bu[3]=xc_[r1o+wm]; bu[4]=xc_[r1o+w]; bu[5]=xc_[r1o+wp];
        bu[6]=xc_[r2o+wm]; bu[7]=xc_[r2o+w]; bu[8]=xc_[r2o+wp];
    }
    #pragma unroll
    for (int pr = 0; pr < 8; pr++) {
        if (pr < 7) {                            // prefetch next pair
            #pragma unroll
            for (int cc = 0; cc < 2; cc++) {
                const float* xc_ = xb + ((pr+1)*2 + cc)*IMG;
                float* bu = &buf[(pr+1)&1][cc*9];
                bu[0]=xc_[r0o+wm]; bu[1]=xc_[r0o+w]; bu[2]=xc_[r0o+wp];
                bu[3]=xc_[r1o+wm]; bu[4]=xc_[r1o+w]; bu[5]=xc_[r1o+wp];
                bu[6]=xc_[r2o+wm]; bu[7]=xc_[r2o+w]; bu[8]=xc_[r2o+wp];
            }
        }
        float pv[6];
        #pragma unroll
        for (int cc = 0; cc < 2; cc++) {         // channels 2pr, 2pr+1
            const float* a = &buf[pr&1][cc*9];
            pv[cc*3+0] = a[4];
            xc[pr*2+cc] = a[4];
            pv[cc*3+1] = 0.125f*(a[2]-a[0]) + 0.25f*(a[5]-a[3]) + 0.125f*(a[8]-a[6]);
            pv[cc*3+2] = 0.125f*(a[6]-a[0]) + 0.25f*(a[7]-a[1]) + 0.125f*(a[8]-a[2]);
            if (pr*2 + cc == 3)                  // fused pre_life pool (alpha)
                premax = fmaxf(fmaxf(fmaxf(a[0],a[1]),fmaxf(a[2],a[3])),
                         fmaxf(fmaxf(a[4],a[5]),fmaxf(fmaxf(a[6],a[7]),a[8])));
        }
        pk[pr*3+0] = packbf2(pv[0], pv[1]);
        pk[pr*3+1] = packbf2(pv[2], pv[3]);
        pk[pr*3+2] = packbf2(pv[4], pv[5]);
    }

    {   // stage p row (48 bf16, 112 B stride) — R3-verbatim
        u32x4* pvv = (u32x4*)(lds + t*P_STRIDE);
        #pragma unroll
        for (int j = 0; j < 6; j++) {
            u32x4 v = {pk[4*j], pk[4*j+1], pk[4*j+2], pk[4*j+3]};
            pvv[j] = v;
        }
    }
    __syncthreads();   // barrier 1: staging complete

    // ---- preload ALL fragments to registers (R3-verbatim) ----
    const int wv = t >> 6, l15 = t & 15, lg = (t >> 4) & 3;

    bf16x8 A1a[8]; bf16x4 A1b[8];                // w1t rows (hidden-major)
    #pragma unroll
    for (int mt = 0; mt < 8; mt++) {
        const unsigned char* r = lds + W1_OFF + (mt*16 + l15)*W1_STRIDE;
        A1a[mt] = *(const bf16x8*)(r + lg*16);
        A1b[mt] = *(const bf16x4*)(r + 64 + lg*8);
    }
    bf16x8 Bpa[4]; bf16x4 Bpb[4];                // p cols (pixel-major)
    #pragma unroll
    for (int pt = 0; pt < 4; pt++) {
        const unsigned char* r = lds + (wv*64 + pt*16 + l15)*P_STRIDE;
        Bpa[pt] = *(const bf16x8*)(r + lg*16);
        Bpb[pt] = *(const bf16x4*)(r + 64 + lg*8);
    }
    bf16x8 A2[4];                                // w2t rows (channel-major)
    #pragma unroll
    for (int kt = 0; kt < 4; kt++)
        A2[kt] = *(const bf16x8*)(lds + W2_OFF + l15*272 + kt*64 + lg*16);
    f32x4 b2frag = *(const f32x4*)(lds + B2_OFF + lg*16);

    asm volatile("s_waitcnt lgkmcnt(0)" ::: "memory");
    __builtin_amdgcn_sched_barrier(0);
    __syncthreads();   // barrier 2: all preloads done; bounce regions free

    unsigned char* hb  = lds + wv*BNC_SZ;            // h  [16 pix][272 B]
    unsigned char* dxb = lds + wv*BNC_SZ + BNC_DX;   // dx [64 pix][80 B]

    #pragma unroll
    for (int pt = 0; pt < 4; pt++) {
        // GEMM1: h[hidden][pixel-tile], bias from LDS into accumulator
        f32x4 hacc[8];
        __builtin_amdgcn_s_setprio(1);
        #pragma unroll
        for (int mt = 0; mt < 8; mt++) {
            f32x4 a = *(const f32x4*)(lds + B1_OFF + (mt*16 + lg*4)*4);
            a = __builtin_amdgcn_mfma_f32_16x16x32_bf16(A1a[mt], Bpa[pt], a, 0,0,0);
            a = mfma_bf16_16x16x16(A1b[mt], Bpb[pt], a);
            hacc[mt] = a;
        }
        __builtin_amdgcn_s_setprio(0);
        // WAR: previous iteration's Bh reads must retire before h overwrite
        asm volatile("s_waitcnt lgkmcnt(0)" ::: "memory");
        __builtin_amdgcn_sched_barrier(0);
        #pragma unroll
        for (int mt = 0; mt < 8; mt++) {
            u32x2 pk2 = {packbf2(fmaxf(hacc[mt][0],0.f), fmaxf(hacc[mt][1],0.f)),
                         packbf2(fmaxf(hacc[mt][2],0.f), fmaxf(hacc[mt][3],0.f))};
            *(u32x2*)(hb + l15*272 + mt*32 + lg*8) = pk2;
        }
        asm volatile("s_waitcnt lgkmcnt(0)" ::: "memory");   // RAW: h
        __builtin_amdgcn_sched_barrier(0);
        // GEMM2: dx[chan][pixel-tile]
        f32x4 acc2 = b2frag;
        __builtin_amdgcn_s_setprio(1);
        #pragma unroll
        for (int kt = 0; kt < 4; kt++) {
            bf16x8 Bh = *(const bf16x8*)(hb + l15*272 + kt*64 + lg*16);
            acc2 = __builtin_amdgcn_mfma_f32_16x16x32_bf16(A2[kt], Bh, acc2, 0,0,0);
        }
        __builtin_amdgcn_s_setprio(0);
        // lane (l15,lg) holds dx[c=4lg+r][pixel=pt*16+l15] -> one b128
        *(f32x4*)(dxb + (pt*16 + l15)*80 + lg*16) = acc2;
    }
    asm volatile("s_waitcnt lgkmcnt(0)" ::: "memory");       // RAW: dx
    __builtin_amdgcn_sched_barrier(0);

    // ---- epilogue: thread t owns wave-local pixel (t&63) = column w=t ----
    const unsigned char* myd = lds + wv*BNC_SZ + BNC_DX + (t & 63)*80;
    float dxv[16];
    *(f32x4*)&dxv[0]  = *(const f32x4*)(myd +  0);
    *(f32x4*)&dxv[4]  = *(const f32x4*)(myd + 16);
    *(f32x4*)&dxv[8]  = *(const f32x4*)(myd + 32);
    *(f32x4*)&dxv[12] = *(const f32x4*)(myd + 48);

    const float fm    = (rv < 0.5f)     ? 1.0f : 0.0f;
    const float lifep = (premax > 0.1f) ? 1.0f : 0.0f;

    alpha_ws[b*IMG + r1o + w] = fmaf(dxv[3], fm, xc[3]);

    float* ob = out + (size_t)b*NC*IMG + r1o + w;
    #pragma unroll
    for (int c = 0; c < 16; c++)
        ob[(size_t)c*IMG] = fmaf(dxv[c], fm, xc[c]) * lifep;
}

// ---------------------------------------------------------------------------
// Pass 2: post_life pool over alpha_new; zero the (rare) dead pixels.
// ---------------------------------------------------------------------------
__global__ __launch_bounds__(256) void nca_postmask(
    const float* __restrict__ alpha_ws, float* __restrict__ out)
{
    const int wg = (blockIdx.x & 7) * 512 + (blockIdx.x >> 3);
    const int b  = wg >> 8;
    const int h  = wg & 255;
    const int w  = threadIdx.x;
    const int hm = (h + 255) & 255, hp = (h + 1) & 255;
    const int wm = (w + 255) & 255, wp = (w + 1) & 255;

    const float* na = alpha_ws + b*IMG;
    const float* n0 = na + hm*256;
    const float* n1 = na + h *256;
    const float* n2 = na + hp*256;
    float post = fmaxf(fmaxf(fmaxf(n0[wm],n0[w]),fmaxf(n0[wp],n1[wm])),
                 fmaxf(fmaxf(n1[w],n1[wp]),fmaxf(fmaxf(n2[wm],n2[w]),n2[wp])));
    if (!(post > 0.1f)) {
        float* ob = out + (size_t)b*NC*IMG + h*256 + w;
        #pragma unroll
        for (int c = 0; c < 16; c++) ob[c*IMG] = 0.0f;
    }
}

extern "C" void kernel_launch(void* const* d_in, const int* in_sizes, int n_in,
                              void* d_out, int out_size, void* d_ws, size_t ws_size,
                              hipStream_t stream) {
    const float* x         = (const float*)d_in[0];
    const float* rand_vals = (const float*)d_in[1];
    const float* w1        = (const float*)d_in[2];
    const float* b1        = (const float*)d_in[3];
    const float* w2        = (const float*)d_in[4];
    const float* b2        = (const float*)d_in[5];
    float* out      = (float*)d_out;
    float* alpha_ws = (float*)d_ws;   // 4 MB

    const int grid = 16 * 256;
    nca_update_mfma<<<grid, 256, 0, stream>>>(x, rand_vals, w1, b1, w2, b2,
                                              out, alpha_ws);
    nca_postmask<<<grid, 256, 0, stream>>>(alpha_ws, out);
}